// Round 1
// baseline (1806.063 us; speedup 1.0000x reference)
//
#include <hip/hip_runtime.h>
#include <math.h>

typedef __attribute__((ext_vector_type(4))) float f32x4;
typedef __attribute__((ext_vector_type(8))) short bf16x8;
typedef __attribute__((ext_vector_type(4))) unsigned short u16x4;

__device__ __forceinline__ unsigned short f2bf(float f) {
  union { float f; unsigned u; } v; v.f = f;
  return (unsigned short)((v.u + 0x7fffu + ((v.u >> 16) & 1u)) >> 16);
}

__device__ __forceinline__ f32x4 zero4() {
  f32x4 z; z[0] = z[1] = z[2] = z[3] = 0.f; return z;
}

__device__ __forceinline__ f32x4 mfma16(bf16x8 a, bf16x8 b, f32x4 c) {
  return __builtin_amdgcn_mfma_f32_16x16x32_bf16(a, b, c, 0, 0, 0);
}

// ---------------------------------------------------------------------------
// K0: convert weights f32 -> bf16 into workspace
// ---------------------------------------------------------------------------
__global__ void cvt_kernel(const float* __restrict__ pw, const float* __restrict__ f1,
                           const float* __restrict__ f2, unsigned short* __restrict__ opw,
                           unsigned short* __restrict__ of1, unsigned short* __restrict__ of2) {
  const long stride = (long)gridDim.x * blockDim.x;
  const long t0 = (long)blockIdx.x * blockDim.x + threadIdx.x;
  for (long i = t0; i < 512L * 512; i += stride) opw[i] = f2bf(pw[i]);
  for (long i = t0; i < 2048L * 512; i += stride) of1[i] = f2bf(f1[i]);
  for (long i = t0; i < 512L * 2048; i += stride) of2[i] = f2bf(f2[i]);
}

// ---------------------------------------------------------------------------
// K1: window attention. grid=1024 windows, 256 thr (4 waves), 4 heads/wave.
// S = (q*scale) @ k^T via mfma (K=32 one step), softmax over cols, + bias
// (AFTER softmax, faithful to ref), O = P @ v via mfma. O -> ws as bf16.
// ---------------------------------------------------------------------------
__global__ __launch_bounds__(256) void attn_kernel(
    const float* __restrict__ q, const float* __restrict__ k,
    const float* __restrict__ v, const float* __restrict__ rpb,
    unsigned short* __restrict__ O) {
  __shared__ float Plds[4][64][68];   // per-wave P buffer, padded (+4) vs bank conflicts
  const int w = blockIdx.x;
  const int tid = threadIdx.x;
  const int wv = tid >> 6;
  const int lane = tid & 63;
  const int l16 = lane & 15;
  const int g = lane >> 4;
  float (*P)[68] = Plds[wv];
  const float scale = 0.17677669529663687f;  // 32^-0.5
  const long base = (long)w * (64 * 512);

  for (int hi = 0; hi < 4; ++hi) {
    const int h = wv * 4 + hi;
    // A (q, scaled) and B (k) fragments: lane -> row (t*16+l16), k = g*8..+7
    bf16x8 aq[4], bk[4];
#pragma unroll
    for (int t = 0; t < 4; ++t) {
      const float* qp = q + base + (long)(t * 16 + l16) * 512 + h * 32 + g * 8;
      const float* kp = k + base + (long)(t * 16 + l16) * 512 + h * 32 + g * 8;
      f32x4 q0 = *(const f32x4*)qp, q1 = *(const f32x4*)(qp + 4);
      f32x4 k0 = *(const f32x4*)kp, k1 = *(const f32x4*)(kp + 4);
#pragma unroll
      for (int j = 0; j < 4; ++j) {
        aq[t][j]     = (short)f2bf(q0[j] * scale);
        aq[t][j + 4] = (short)f2bf(q1[j] * scale);
        bk[t][j]     = (short)f2bf(k0[j]);
        bk[t][j + 4] = (short)f2bf(k1[j]);
      }
    }
    f32x4 acc[4][4];
#pragma unroll
    for (int a = 0; a < 4; ++a)
#pragma unroll
      for (int b = 0; b < 4; ++b) acc[a][b] = zero4();
#pragma unroll
    for (int a = 0; a < 4; ++a)
#pragma unroll
      for (int b = 0; b < 4; ++b) acc[a][b] = mfma16(aq[a], bk[b], acc[a][b]);

    // softmax over the 64 columns of each row, then + rel-pos bias, store to LDS
#pragma unroll
    for (int tm = 0; tm < 4; ++tm) {
      f32x4 mx;
#pragma unroll
      for (int i = 0; i < 4; ++i)
        mx[i] = fmaxf(fmaxf(acc[tm][0][i], acc[tm][1][i]),
                      fmaxf(acc[tm][2][i], acc[tm][3][i]));
#pragma unroll
      for (int off = 1; off < 16; off <<= 1)
#pragma unroll
        for (int i = 0; i < 4; ++i)
          mx[i] = fmaxf(mx[i], __shfl_xor(mx[i], off, 64));
      f32x4 sm = zero4();
#pragma unroll
      for (int tc = 0; tc < 4; ++tc)
#pragma unroll
        for (int i = 0; i < 4; ++i) {
          acc[tm][tc][i] = __expf(acc[tm][tc][i] - mx[i]);
          sm[i] += acc[tm][tc][i];
        }
#pragma unroll
      for (int off = 1; off < 16; off <<= 1)
#pragma unroll
        for (int i = 0; i < 4; ++i) sm[i] += __shfl_xor(sm[i], off, 64);
      f32x4 inv;
#pragma unroll
      for (int i = 0; i < 4; ++i) inv[i] = 1.0f / sm[i];
#pragma unroll
      for (int tc = 0; tc < 4; ++tc)
#pragma unroll
        for (int i = 0; i < 4; ++i) {
          int n = tm * 16 + g * 4 + i;   // query token (row)
          int m = tc * 16 + l16;         // key token (col)
          int idx = ((n >> 3) - (m >> 3) + 7) * 15 + ((n & 7) - (m & 7) + 7);
          P[n][m] = acc[tm][tc][i] * inv[i] + rpb[idx * 16 + h];
        }
    }

    // O = P @ vh   (M=64 x N=32 x K=64 -> 4x2 tiles, 2 k-steps)
    f32x4 oc[4][2];
#pragma unroll
    for (int a = 0; a < 4; ++a) { oc[a][0] = zero4(); oc[a][1] = zero4(); }
#pragma unroll
    for (int ks = 0; ks < 2; ++ks) {
      bf16x8 ap[4];
#pragma unroll
      for (int tm = 0; tm < 4; ++tm) {
        const float* pp = &P[tm * 16 + l16][ks * 32 + g * 8];
        f32x4 p0 = *(const f32x4*)pp, p1 = *(const f32x4*)(pp + 4);
#pragma unroll
        for (int j = 0; j < 4; ++j) {
          ap[tm][j]     = (short)f2bf(p0[j]);
          ap[tm][j + 4] = (short)f2bf(p1[j]);
        }
      }
      bf16x8 bv[2];
#pragma unroll
      for (int tn = 0; tn < 2; ++tn)
#pragma unroll
        for (int j = 0; j < 8; ++j) {
          int m = ks * 32 + g * 8 + j;
          bv[tn][j] = (short)f2bf(v[base + (long)m * 512 + h * 32 + tn * 16 + l16]);
        }
#pragma unroll
      for (int tm = 0; tm < 4; ++tm)
#pragma unroll
        for (int tn = 0; tn < 2; ++tn) oc[tm][tn] = mfma16(ap[tm], bv[tn], oc[tm][tn]);
    }
#pragma unroll
    for (int tm = 0; tm < 4; ++tm)
#pragma unroll
      for (int tn = 0; tn < 2; ++tn)
#pragma unroll
        for (int i = 0; i < 4; ++i) {
          int n = tm * 16 + g * 4 + i;
          O[base + (long)n * 512 + h * 32 + tn * 16 + l16] = f2bf(oc[tm][tn][i]);
        }
  }
}

// ---------------------------------------------------------------------------
// K2: proj GEMM (per window 64x512x512) + bias + gamma1*() + x residual,
// scattered (window_reverse) into y == d_out (f32).
// ---------------------------------------------------------------------------
__global__ __launch_bounds__(256) void proj_kernel(
    const unsigned short* __restrict__ O, const unsigned short* __restrict__ pw,
    const float* __restrict__ pb, const float* __restrict__ gamma1,
    const float* __restrict__ x, float* __restrict__ y) {
  const int w = blockIdx.x;
  const int tid = threadIdx.x;
  const int wv = tid >> 6, lane = tid & 63;
  const int l16 = lane & 15, g = lane >> 4;
  const long obase = (long)w * (64 * 512);
  f32x4 acc[4][8];
#pragma unroll
  for (int a = 0; a < 4; ++a)
#pragma unroll
    for (int b = 0; b < 8; ++b) acc[a][b] = zero4();

  for (int kk = 0; kk < 512; kk += 32) {
    bf16x8 a[4];
#pragma unroll
    for (int tm = 0; tm < 4; ++tm)
      a[tm] = *(const bf16x8*)(O + obase + (long)(tm * 16 + l16) * 512 + kk + g * 8);
#pragma unroll
    for (int tn = 0; tn < 8; ++tn) {
      int c = wv * 128 + tn * 16 + l16;
      bf16x8 b = *(const bf16x8*)(pw + (long)c * 512 + kk + g * 8);
#pragma unroll
      for (int tm = 0; tm < 4; ++tm) acc[tm][tn] = mfma16(a[tm], b, acc[tm][tn]);
    }
  }
  const int bi = w >> 6, wh = (w >> 3) & 7, wc = w & 7;
#pragma unroll
  for (int tn = 0; tn < 8; ++tn) {
    int c = wv * 128 + tn * 16 + l16;
    float g1c = gamma1[c], pbc = pb[c];
#pragma unroll
    for (int tm = 0; tm < 4; ++tm)
#pragma unroll
      for (int i = 0; i < 4; ++i) {
        int n = tm * 16 + g * 4 + i;
        long t = (long)(bi * 64 + wh * 8 + (n >> 3)) * 64 + wc * 8 + (n & 7);
        y[t * 512 + c] = x[t * 512 + c] + g1c * (acc[tm][tn][i] + pbc);
      }
  }
}

// ---------------------------------------------------------------------------
// K3: LN2 + fused MLP (512->2048 GELU ->512) + gamma2 residual, in-place on y.
// 64 tokens/block; yn bf16 + chunked h1 staged in LDS.
// ---------------------------------------------------------------------------
__global__ __launch_bounds__(256) void mlp_kernel(
    float* __restrict__ y,
    const unsigned short* __restrict__ f1w, const float* __restrict__ f1b,
    const unsigned short* __restrict__ f2w, const float* __restrict__ f2b,
    const float* __restrict__ lnw, const float* __restrict__ lnb,
    const float* __restrict__ g2) {
  __shared__ unsigned short yn[64][520];
  __shared__ unsigned short h1[64][264];
  __shared__ float stats[64][8];
  __shared__ float murs[64][2];
  const int tid = threadIdx.x;
  const long T0 = (long)blockIdx.x * 64;

  {  // LN pass 1: per-row sums
    const int r = tid >> 2, sg = tid & 3;
    const float* yr = y + (T0 + r) * 512 + sg * 128;
    float s = 0.f, s2 = 0.f;
    for (int j = 0; j < 128; j += 4) {
      f32x4 t = *(const f32x4*)(yr + j);
      s += t[0] + t[1] + t[2] + t[3];
      s2 += t[0] * t[0] + t[1] * t[1] + t[2] * t[2] + t[3] * t[3];
    }
    stats[r][sg] = s; stats[r][sg + 4] = s2;
  }
  __syncthreads();
  if (tid < 64) {
    float ss = stats[tid][0] + stats[tid][1] + stats[tid][2] + stats[tid][3];
    float q2 = stats[tid][4] + stats[tid][5] + stats[tid][6] + stats[tid][7];
    float mu = ss * (1.f / 512.f);
    float var = q2 * (1.f / 512.f) - mu * mu;
    murs[tid][0] = mu;
    murs[tid][1] = rsqrtf(var + 1e-5f);
  }
  __syncthreads();
  {  // LN pass 2: normalize -> yn (bf16)
    const int r = tid >> 2, sg = tid & 3;
    const float mu = murs[r][0], rs = murs[r][1];
    const float* yr = y + (T0 + r) * 512 + sg * 128;
    for (int j = 0; j < 128; j += 4) {
      f32x4 t = *(const f32x4*)(yr + j);
      f32x4 wv4 = *(const f32x4*)(lnw + sg * 128 + j);
      f32x4 bv4 = *(const f32x4*)(lnb + sg * 128 + j);
      u16x4 o;
#pragma unroll
      for (int e = 0; e < 4; ++e) o[e] = f2bf((t[e] - mu) * rs * wv4[e] + bv4[e]);
      *(u16x4*)&yn[r][sg * 128 + j] = o;
    }
  }
  __syncthreads();

  const int wv = tid >> 6, lane = tid & 63;
  const int l16 = lane & 15, g = lane >> 4;
  f32x4 acc[4][8];
#pragma unroll
  for (int a = 0; a < 4; ++a)
#pragma unroll
    for (int b = 0; b < 8; ++b) acc[a][b] = zero4();

  for (int ic = 0; ic < 8; ++ic) {
    const int ib = ic * 256;
    // fc1: this wave computes h1[:, ib + wv*64 .. +64)
    f32x4 acc2[4][4];
#pragma unroll
    for (int a = 0; a < 4; ++a)
#pragma unroll
      for (int b = 0; b < 4; ++b) acc2[a][b] = zero4();
    for (int kk = 0; kk < 512; kk += 32) {
      bf16x8 a[4];
#pragma unroll
      for (int tm = 0; tm < 4; ++tm)
        a[tm] = *(const bf16x8*)&yn[tm * 16 + l16][kk + g * 8];
#pragma unroll
      for (int tn = 0; tn < 4; ++tn) {
        long irow = ib + wv * 64 + tn * 16 + l16;
        bf16x8 b = *(const bf16x8*)(f1w + irow * 512 + kk + g * 8);
#pragma unroll
        for (int tm = 0; tm < 4; ++tm) acc2[tm][tn] = mfma16(a[tm], b, acc2[tm][tn]);
      }
    }
    __syncthreads();  // prev chunk's h1 fully consumed by all waves
#pragma unroll
    for (int tm = 0; tm < 4; ++tm)
#pragma unroll
      for (int tn = 0; tn < 4; ++tn)
#pragma unroll
        for (int i = 0; i < 4; ++i) {
          int row = tm * 16 + g * 4 + i;
          int cl = wv * 64 + tn * 16 + l16;
          float val = acc2[tm][tn][i] + f1b[ib + cl];
          float gg = 0.5f * val * (1.f + erff(val * 0.70710678118654752f));  // exact GELU
          h1[row][cl] = f2bf(gg);
        }
    __syncthreads();  // h1 ready
    // fc2: accumulate this wave's 128 output cols over this inner chunk
    for (int kk = 0; kk < 256; kk += 32) {
      bf16x8 a[4];
#pragma unroll
      for (int tm = 0; tm < 4; ++tm)
        a[tm] = *(const bf16x8*)&h1[tm * 16 + l16][kk + g * 8];
#pragma unroll
      for (int tn = 0; tn < 8; ++tn) {
        int c = wv * 128 + tn * 16 + l16;
        bf16x8 b = *(const bf16x8*)(f2w + (long)c * 2048 + ib + kk + g * 8);
#pragma unroll
        for (int tm = 0; tm < 4; ++tm) acc[tm][tn] = mfma16(a[tm], b, acc[tm][tn]);
      }
    }
  }
#pragma unroll
  for (int tn = 0; tn < 8; ++tn) {
    int c = wv * 128 + tn * 16 + l16;
    float g2c = g2[c], fbc = f2b[c];
#pragma unroll
    for (int tm = 0; tm < 4; ++tm)
#pragma unroll
      for (int i = 0; i < 4; ++i) {
        long t = T0 + tm * 16 + g * 4 + i;
        y[t * 512 + c] += g2c * (acc[tm][tn][i] + fbc);
      }
  }
}

// ---------------------------------------------------------------------------
extern "C" void kernel_launch(void* const* d_in, const int* in_sizes, int n_in,
                              void* d_out, int out_size, void* d_ws, size_t ws_size,
                              hipStream_t stream) {
  const float* x   = (const float*)d_in[0];
  const float* q   = (const float*)d_in[1];
  const float* k   = (const float*)d_in[2];
  const float* v   = (const float*)d_in[3];
  const float* pw  = (const float*)d_in[4];
  const float* pb  = (const float*)d_in[5];
  const float* rpb = (const float*)d_in[6];
  const float* g1  = (const float*)d_in[7];
  const float* lnw = (const float*)d_in[8];
  const float* lnb = (const float*)d_in[9];
  const float* f1w = (const float*)d_in[10];
  const float* f1b = (const float*)d_in[11];
  const float* f2w = (const float*)d_in[12];
  const float* f2b = (const float*)d_in[13];
  const float* g2  = (const float*)d_in[14];
  float* y = (float*)d_out;  // y (post-attn residual) lives in d_out, then finalized in-place

  unsigned short* Ob   = (unsigned short*)d_ws;            // 1024*64*512 bf16 = 64 MB
  unsigned short* pwb  = Ob + (size_t)1024 * 64 * 512;     // 512*512
  unsigned short* f1wb = pwb + 512 * 512;                  // 2048*512
  unsigned short* f2wb = f1wb + 2048 * 512;                // 512*2048

  hipLaunchKernelGGL(cvt_kernel, dim3(1024), dim3(256), 0, stream,
                     pw, f1w, f2w, pwb, f1wb, f2wb);
  hipLaunchKernelGGL(attn_kernel, dim3(1024), dim3(256), 0, stream,
                     q, k, v, rpb, Ob);
  hipLaunchKernelGGL(proj_kernel, dim3(1024), dim3(256), 0, stream,
                     Ob, pwb, pb, g1, x, y);
  hipLaunchKernelGGL(mlp_kernel, dim3(1024), dim3(256), 0, stream,
                     y, f1wb, f1b, f2wb, f2b, lnw, lnb, g2);
}